// Round 12
// baseline (289.709 us; speedup 1.0000x reference)
//
#include <hip/hip_runtime.h>

#define S_LEN 2048
#define D_DIM 2048
#define NH 16
#define HD 128
#define NB 2
#define NROW (NB * S_LEN)  // 4096
#define QKV_STR 6144       // fused Q|K|V row stride (V slice unused/unwritten)

typedef unsigned short bf16;
typedef __attribute__((ext_vector_type(8))) short bf16x8;
typedef __attribute__((ext_vector_type(4))) float f32x4;
typedef __attribute__((ext_vector_type(16))) float f32x16;
typedef __attribute__((address_space(3))) unsigned int as3u;
typedef __attribute__((address_space(1))) unsigned int as1u;

__device__ __forceinline__ void gload16(const void* g, void* l) {
  __builtin_amdgcn_global_load_lds((const as1u*)g, (as3u*)l, 16, 0, 0);
}

__device__ __forceinline__ unsigned short f2bf(float f) {
  unsigned u = __builtin_bit_cast(unsigned, f);
  u += 0x7FFFu + ((u >> 16) & 1u);
  return (unsigned short)(u >> 16);
}
__device__ __forceinline__ float bf2f(unsigned short b) {
  return __builtin_bit_cast(float, (unsigned)b << 16);
}
__device__ __forceinline__ unsigned cvtpk(float lo, float hi) {
  unsigned r;
  asm("v_cvt_pk_bf16_f32 %0, %1, %2" : "=v"(r) : "v"(lo), "v"(hi));
  return r;
}
__device__ __forceinline__ float exp2a(float x) {  // 2^x
  float r;
  asm("v_exp_f32 %0, %1" : "=v"(r) : "v"(x));
  return r;
}

// ---------------- small prep kernels ----------------

__global__ void rope_table_k(float2* __restrict__ tab) {
  int i = blockIdx.x * 256 + threadIdx.x;  // S*64
  int s = i >> 6, d = i & 63;
  float invf = powf(10000.0f, -(float)d * (1.0f / 64.0f));
  float ang = (float)s * invf;
  tab[i] = make_float2(cosf(ang), sinf(ang));
}

__global__ void convert_x_k(const float* __restrict__ src, bf16* __restrict__ dst) {
  int i = (blockIdx.x * 256 + threadIdx.x) * 4;
  float4 v = *(const float4*)(src + i);
  ushort4 w;
  w.x = f2bf(v.x); w.y = f2bf(v.y); w.z = f2bf(v.z); w.w = f2bf(v.w);
  *(ushort4*)(dst + i) = w;
}

// all 4 weight transposes in one launch: z in {0:wq,1:wk,2:wv,3:wo}
__global__ void transpose_w_k(const float* __restrict__ w0, const float* __restrict__ w1,
                              const float* __restrict__ w2, const float* __restrict__ w3,
                              bf16* __restrict__ wTall, bf16* __restrict__ wTo) {
  __shared__ float t[64][65];
  int z = blockIdx.z;
  const float* W = (z == 0) ? w0 : (z == 1) ? w1 : (z == 2) ? w2 : w3;
  bf16* Wt = (z == 3) ? wTo : wTall + (size_t)z * 2048 * D_DIM;
  int c0 = blockIdx.x * 64, r0 = blockIdx.y * 64;
  int tx = threadIdx.x & 63, ty = threadIdx.x >> 6;
#pragma unroll
  for (int i = 0; i < 16; ++i)
    t[ty + i * 4][tx] = W[(size_t)(r0 + ty + i * 4) * D_DIM + c0 + tx];
  __syncthreads();
#pragma unroll
  for (int i = 0; i < 16; ++i)
    Wt[(size_t)(c0 + ty + i * 4) * D_DIM + r0 + tx] = f2bf(t[tx][ty + i * 4]);
}

// ---------------- 128x128 GEMM, BK=64 (m97 structure; WO projection) ---------

__device__ __forceinline__ void storec(bf16* p, float v) { *p = f2bf(v); }
__device__ __forceinline__ void storec(float* p, float v) { *p = v; }

template <typename OutT>
__global__ __launch_bounds__(256) void gemm_bt_k(
    const bf16* __restrict__ A, const bf16* __restrict__ Bt,
    OutT* __restrict__ C, int M, int N, int K) {
  __shared__ bf16 As[128 * 64];
  __shared__ bf16 Bs[128 * 64];
  const int tid = threadIdx.x;
  const int lane = tid & 63;
  const int wid = tid >> 6;
  const int bm = blockIdx.y * 128;
  const int bn = blockIdx.x * 128;
  const int wr = (wid >> 1) * 64;
  const int wc = (wid & 1) * 64;
  const int lr = lane & 15;
  const int kg = lane >> 4;

  f32x4 acc[4][4] = {};

  const int srow = lane >> 3;
  const int scol = ((lane & 7) ^ srow) * 8;
  const bf16* Ap = A + (size_t)(bm + wid * 32 + srow) * K + scol;
  const bf16* Bp = Bt + (size_t)(bn + wid * 32 + srow) * K + scol;
  bf16* Asd = &As[wid * 32 * 64];
  bf16* Bsd = &Bs[wid * 32 * 64];

  const int rx = (lr & 7) << 4;

  for (int k0 = 0; k0 < K; k0 += 64) {
    __syncthreads();
#pragma unroll
    for (int p = 0; p < 4; ++p) {
      gload16(Ap + (size_t)(p * 8) * K + k0, Asd + p * 8 * 64);
      gload16(Bp + (size_t)(p * 8) * K + k0, Bsd + p * 8 * 64);
    }
    __syncthreads();
    bf16x8 a[4][2], b[4][2];
#pragma unroll
    for (int m = 0; m < 4; ++m) {
      const char* rowp = (const char*)&As[(wr + m * 16 + lr) * 64];
#pragma unroll
      for (int kk = 0; kk < 2; ++kk)
        a[m][kk] = *(const bf16x8*)(rowp + ((kk * 64 + kg * 16) ^ rx));
    }
#pragma unroll
    for (int n = 0; n < 4; ++n) {
      const char* rowp = (const char*)&Bs[(wc + n * 16 + lr) * 64];
#pragma unroll
      for (int kk = 0; kk < 2; ++kk)
        b[n][kk] = *(const bf16x8*)(rowp + ((kk * 64 + kg * 16) ^ rx));
    }
#pragma unroll
    for (int kk = 0; kk < 2; ++kk)
#pragma unroll
      for (int m = 0; m < 4; ++m)
#pragma unroll
        for (int n = 0; n < 4; ++n)
          acc[m][n] = __builtin_amdgcn_mfma_f32_16x16x32_bf16(a[m][kk], b[n][kk], acc[m][n], 0, 0, 0);
  }

#pragma unroll
  for (int m = 0; m < 4; ++m) {
    int row0 = bm + wr + m * 16 + kg * 4;
#pragma unroll
    for (int n = 0; n < 4; ++n) {
      int col = bn + wc + n * 16 + lr;
#pragma unroll
      for (int r = 0; r < 4; ++r)
        storec(&C[(size_t)(row0 + r) * N + col], acc[m][n][r]);
    }
  }
}

// ---------------- QKV GEMM with fused RoPE + V-transpose epilogue ------------
// BK=64 main loop; wave column fragments remapped so each wave owns BOTH d and
// d+64 of a head: bcol(n) = wc2 + (n&1)*16 + (n>>1)*64. RoPE in f32 in-register.
// Epilogue bounces the finished 128x128 tile through LDS (reusing the 32KB
// As/Bs region, XOR swizzle byte^=(row&7)<<4) so all global stores are dense
// 16B: Q/K row-major into QKV; V in [d][s] layout into Vt.
__global__ __launch_bounds__(256) void gemm_qkv_k(
    const bf16* __restrict__ A, const bf16* __restrict__ Bt,
    bf16* __restrict__ QKV, bf16* __restrict__ Vt,
    const float2* __restrict__ tab) {
  const int K = 2048;
  __shared__ bf16 smem[16384];  // 32KB: As @0, Bs @8192; epilogue reuses all
  bf16* As = smem;
  bf16* Bs = smem + 8192;
  const int tid = threadIdx.x;
  const int lane = tid & 63;
  const int wid = tid >> 6;
  const int bm = blockIdx.y * 128;
  const int bn = blockIdx.x * 128;
  const int wr = (wid >> 1) * 64;
  const int wc2 = (wid & 1) * 32;
  const int lr = lane & 15;
  const int kg = lane >> 4;

  f32x4 acc[4][4] = {};

  const int srow = lane >> 3;
  const int scol = ((lane & 7) ^ srow) * 8;
  const bf16* Ap = A + (size_t)(bm + wid * 32 + srow) * K + scol;
  const bf16* Bp = Bt + (size_t)(bn + wid * 32 + srow) * K + scol;
  bf16* Asd = &As[wid * 32 * 64];
  bf16* Bsd = &Bs[wid * 32 * 64];

  const int rx = (lr & 7) << 4;

  for (int k0 = 0; k0 < K; k0 += 64) {
    __syncthreads();
#pragma unroll
    for (int p = 0; p < 4; ++p) {
      gload16(Ap + (size_t)(p * 8) * K + k0, Asd + p * 8 * 64);
      gload16(Bp + (size_t)(p * 8) * K + k0, Bsd + p * 8 * 64);
    }
    __syncthreads();
    bf16x8 a[4][2], b[4][2];
#pragma unroll
    for (int m = 0; m < 4; ++m) {
      const char* rowp = (const char*)&As[(wr + m * 16 + lr) * 64];
#pragma unroll
      for (int kk = 0; kk < 2; ++kk)
        a[m][kk] = *(const bf16x8*)(rowp + ((kk * 64 + kg * 16) ^ rx));
    }
#pragma unroll
    for (int n = 0; n < 4; ++n) {
      int bcol = wc2 + (n & 1) * 16 + (n >> 1) * 64;  // remapped col fragment
      const char* rowp = (const char*)&Bs[(bcol + lr) * 64];
#pragma unroll
      for (int kk = 0; kk < 2; ++kk)
        b[n][kk] = *(const bf16x8*)(rowp + ((kk * 64 + kg * 16) ^ rx));
    }
#pragma unroll
    for (int kk = 0; kk < 2; ++kk)
#pragma unroll
      for (int m = 0; m < 4; ++m)
#pragma unroll
        for (int n = 0; n < 4; ++n)
          acc[m][n] = __builtin_amdgcn_mfma_f32_16x16x32_bf16(a[m][kk], b[n][kk], acc[m][n], 0, 0, 0);
  }

  __syncthreads();  // all main-loop LDS reads done before epilogue reuse
  char* eb = (char*)smem;  // [128 rows][256B], byte ^= (row&7)<<4

  if (bn < 4096) {
    // Q or K tile: fused RoPE (pair d, d+64 in-lane), LDS row-major [s][d]
    const float sc = (bn < 2048) ? 0.12751743f : 1.0f;  // rsqrt(128)*log2e
#pragma unroll
    for (int m = 0; m < 4; ++m) {
      int sl = wr + m * 16 + kg * 4;
#pragma unroll
      for (int j = 0; j < 2; ++j) {
        int d = wc2 + j * 16 + lr;  // 0..63
#pragma unroll
        for (int r = 0; r < 4; ++r) {
          int row = sl + r;
          int s_pos = (bm + row) & (S_LEN - 1);
          float2 cs = tab[s_pos * 64 + d];
          float x1 = acc[m][j][r], x2 = acc[m][j + 2][r];
          char* base = eb + row * 256;
          *(bf16*)(base + ((d * 2) ^ ((row & 7) << 4)))        = f2bf((x1 * cs.x - x2 * cs.y) * sc);
          *(bf16*)(base + (((d + 64) * 2) ^ ((row & 7) << 4))) = f2bf((x2 * cs.x + x1 * cs.y) * sc);
        }
      }
    }
    __syncthreads();
    int row = tid >> 1, ch = (tid & 1) * 64;
    bf16* dst = QKV + (size_t)(bm + row) * QKV_STR + bn + ch;
    char* src = eb + row * 256;
#pragma unroll
    for (int i = 0; i < 8; ++i) {
      int c = ch + i * 8;
      *(bf16x8*)(dst + i * 8) = *(const bf16x8*)(src + ((c * 2) ^ ((row & 7) << 4)));
    }
  } else {
    // V tile: LDS [d][s], then dense 16B stores along s into Vt[bh][d][s]
#pragma unroll
    for (int m = 0; m < 4; ++m) {
      int sl = wr + m * 16 + kg * 4;
#pragma unroll
      for (int n = 0; n < 4; ++n) {
        int d = wc2 + (n & 1) * 16 + (n >> 1) * 64 + lr;
        ushort4 pk;
        pk.x = f2bf(acc[m][n][0]); pk.y = f2bf(acc[m][n][1]);
        pk.z = f2bf(acc[m][n][2]); pk.w = f2bf(acc[m][n][3]);
        *(ushort4*)(eb + d * 256 + ((sl * 2) ^ ((d & 7) << 4))) = pk;
      }
    }
    __syncthreads();
    int b = bm >> 11;
    int h = (bn - 4096) >> 7;
    bf16* vt = Vt + (size_t)(b * 16 + h) * HD * S_LEN;
    int d = tid >> 1, sh2 = (tid & 1) * 64;
    int sbase = bm & (S_LEN - 1);
    char* src = eb + d * 256;
#pragma unroll
    for (int i = 0; i < 8; ++i) {
      int s = sh2 + i * 8;
      *(bf16x8*)(vt + (size_t)d * S_LEN + sbase + s) =
          *(const bf16x8*)(src + ((s * 2) ^ ((d & 7) << 4)));
    }
  }
}

// ---------------- causal flash attention, 32x32 swapped, counted-vmcnt -------
// LDS 80KB: K triple-buffered, V double-buffered; 2 blocks/CU. Complementary
// strip lengths balance CU slot-pairs. T5 setprio around MFMA clusters.
#define FBODY(T, CUR0, CUR1, NXT0, NXT1)                                         \
  {                                                                              \
    const int kv0_ = (T) * 64;                                                   \
    stageV(kv0_ + 64, ((T) + 1) & 1);                                            \
    stageK(kv0_ + 192, kb_st);                                                   \
    kb_st = (kb_st == 2) ? 0 : kb_st + 1;                                        \
    if (kv0_ + 64 <= qw0 + 31) {                                                 \
      NXT0 = 0.0f; NXT1 = 0.0f;                                                  \
      const bf16* krow0_ = &sh[kb_rd * 8192] + (size_t)l31 * 128;                \
      const bf16* krow1_ = krow0_ + 32 * 128;                                    \
      __builtin_amdgcn_s_setprio(1);                                             \
      _Pragma("unroll")                                                          \
      for (int ks = 0; ks < 8; ++ks) {                                           \
        int cb_ = ((ks * 32) ^ kxor) >> 1;                                       \
        bf16x8 kf0_ = *(const bf16x8*)(krow0_ + cb_);                            \
        bf16x8 kf1_ = *(const bf16x8*)(krow1_ + cb_);                            \
        NXT0 = __builtin_amdgcn_mfma_f32_32x32x16_bf16(kf0_, qf[ks], NXT0, 0, 0, 0); \
        NXT1 = __builtin_amdgcn_mfma_f32_32x32x16_bf16(kf1_, qf[ks], NXT1, 0, 0, 0); \
      }                                                                          \
      __builtin_amdgcn_s_setprio(0);                                             \
    }                                                                            \
    kb_rd = (kb_rd == 2) ? 0 : kb_rd + 1;                                        \
    if (kv0_ <= qw0 + 31) {                                                      \
      if (kv0_ + 63 > qw0) {                                                     \
        _Pragma("unroll")                                                        \
        for (int r = 0; r < 16; ++r) {                                           \
          int kvg_ = kv0_ + (r & 3) + 8 * (r >> 2) + 4 * h;                      \
          if (kvg_ > q) CUR0[r] = -3.0e38f;                                      \
          if (kvg_ + 32 > q) CUR1[r] = -3.0e38f;                                 \
        }                                                                        \
      }                                                                          \
      float tm_[8];                                                              \
      _Pragma("unroll")                                                          \
      for (int r = 0; r < 8; ++r)                                                \
        tm_[r] = fmaxf(fmaxf(CUR0[r], CUR0[r + 8]), fmaxf(CUR1[r], CUR1[r + 8])); \
      _Pragma("unroll")                                                          \
      for (int r = 0; r < 4; ++r) tm_[r] = fmaxf(tm_[r], tm_[r + 4]);            \
      float mt_ = fmaxf(fmaxf(tm_[0], tm_[1]), fmaxf(tm_[2], tm_[3]));           \
      mt_ = fmaxf(mt_, __shfl_xor(mt_, 32));                                     \
      if (__any(mt_ > m_run + 8.0f)) {                                           \
        float mnew_ = fmaxf(m_run, mt_);                                         \
        float alpha_ = exp2a(m_run - mnew_);                                     \
        l_run *= alpha_;                                                         \
        _Pragma("unroll")                                                        \
        for (int n = 0; n < 4; ++n)                                              \
          _Pragma("unroll")                                                      \
          for (int r = 0; r < 16; ++r) ot[n][r] *= alpha_;                       \
        m_run = mnew_;                                                           \
      }                                                                          \
      float rs_[16];                                                             \
      _Pragma("unroll")                                                          \
      for (int r = 0; r < 16; ++r) {                                             \
        CUR0[r] = exp2a(CUR0[r] - m_run);                                        \
        CUR1[r] = exp2a(CUR1[r] - m_run);                                        \
        rs_[r] = CUR0[r] + CUR1[r];                                              \
      }                                                                          \
      _Pragma("unroll")                                                          \
      for (int r = 0; r < 8; ++r) rs_[r] += rs_[r + 8];                          \
      _Pragma("unroll")                                                          \
      for (int r = 0; r < 4; ++r) rs_[r] += rs_[r + 4];                          \
      float rsum_ = (rs_[0] + rs_[1]) + (rs_[2] + rs_[3]);                       \
      rsum_ += __shfl_xor(rsum_, 32);                                            \
      l_run += rsum_;                                                            \
      unsigned wd0_[8], wd1_[8];                                                 \
      _Pragma("unroll")                                                          \
      for (int j = 0; j < 8; ++j) {                                              \
        wd0_[j] = cvtpk(CUR0[2 * j], CUR0[2 * j + 1]);                           \
        wd1_[j] = cvtpk(CUR1[2 * j], CUR1[2 * j + 1]);                           \
      }                                                                          \
      const bf16* Vbuf_ = &sh[24576 + ((T) & 1) * 8192];                         \
      __builtin_amdgcn_s_setprio(1);                                             \
      _Pragma("unroll")                                                          \
      for (int t4 = 0; t4 < 4; ++t4) {                                           \
        const unsigned* wdp_ = (t4 >> 1) ? wd1_ : wd0_;                          \
        int a0_ = 4 * (t4 & 1) + 2 * h;                                          \
        int sidx_ = 4 * (t4 & 1) + 2 * (1 - h);                                  \
        unsigned s0_ = (unsigned)__shfl_xor((int)wdp_[sidx_], 32);               \
        unsigned s1_ = (unsigned)__shfl_xor((int)wdp_[sidx_ + 1], 32);           \
        unsigned pb4_[4];                                                        \
        pb4_[0] = h ? s0_ : wdp_[a0_];                                           \
        pb4_[1] = h ? s1_ : wdp_[a0_ + 1];                                       \
        pb4_[2] = h ? wdp_[a0_] : s0_;                                           \
        pb4_[3] = h ? wdp_[a0_ + 1] : s1_;                                       \
        bf16x8 pb_ = __builtin_bit_cast(bf16x8, *(uint4*)pb4_);                  \
        int cb_ = ((t4 * 32) ^ vxor) >> 1;                                       \
        _Pragma("unroll")                                                        \
        for (int n = 0; n < 4; ++n) {                                            \
          bf16x8 va_ = *(const bf16x8*)(Vbuf_ + (size_t)(32 * n + l31) * 64 + cb_); \
          ot[n] = __builtin_amdgcn_mfma_f32_32x32x16_bf16(va_, pb_, ot[n], 0, 0, 0); \
        }                                                                        \
      }                                                                          \
      __builtin_amdgcn_s_setprio(0);                                             \
    }                                                                            \
    asm volatile("s_waitcnt vmcnt(4)" ::: "memory");                             \
    __builtin_amdgcn_sched_barrier(0);                                           \
    __builtin_amdgcn_s_barrier();                                                \
  }

__global__ __launch_bounds__(256, 2) void flash_attn_k(
    const bf16* __restrict__ Q, const bf16* __restrict__ Kb,
    const bf16* __restrict__ Vt, bf16* __restrict__ O) {
  __shared__ bf16 sh[40960];  // 80KB: K0/K1/K2 @0/8192/16384, V0/V1 @24576/32768
  const int tid = threadIdx.x;
  const int lane = tid & 63;
  const int w = tid >> 6;
  const int h = lane >> 5;
  const int l31 = lane & 31;
  const int bh = blockIdx.y;
  const int b = bh >> 4;
  const int hh = bh & 15;
  // complementary strip mapping: bh<16 long-first, bh>=16 short-first
  const int xr = (bh & 16) ? blockIdx.x : (gridDim.x - 1 - blockIdx.x);
  const int qb = xr * 128;
  const int qw0 = qb + 32 * w;
  const int q = qw0 + l31;

  const bf16* qp = Q + (size_t)(b * S_LEN + q) * QKV_STR + hh * HD + h * 8;
  bf16x8 qf[8];
#pragma unroll
  for (int ks = 0; ks < 8; ++ks) qf[ks] = *(const bf16x8*)(qp + ks * 16);

  f32x16 ot[4] = {};
  float m_run = -3.0e38f, l_run = 0.f;

  const bf16* Kg = Kb + (size_t)(b * S_LEN) * QKV_STR + hh * HD;
  const bf16* Vg = Vt + (size_t)bh * HD * S_LEN;

  const int kst_row = 16 * w + (lane >> 4);
  const int vst_row = 32 * w + (lane >> 3);
  const int vst_col = (((lane & 7) ^ (lane >> 3)) << 3);
  const int kxor = (16 * h) ^ ((l31 & 15) << 4);
  const int vxor = (16 * h) ^ ((l31 & 7) << 4);

  auto stageK = [&](int kv0, int buf) {
#pragma unroll
    for (int jj = 0; jj < 4; ++jj) {
      int kr = (kv0 + kst_row + jj * 4) & (S_LEN - 1);
      gload16(Kg + (size_t)kr * QKV_STR + (((lane & 15) ^ (jj * 4 + (lane >> 4))) << 3),
              &sh[buf * 8192 + (16 * w + jj * 4) * 128]);
    }
  };
  auto stageV = [&](int kv0, int buf) {
    int c = (kv0 & (S_LEN - 1)) + vst_col;
#pragma unroll
    for (int jj = 0; jj < 4; ++jj) {
      int vr = vst_row + jj * 8;
      gload16(Vg + (size_t)vr * S_LEN + c, &sh[24576 + buf * 8192 + (32 * w + jj * 8) * 64]);
    }
  };

  // prologue: K(0),V(0),K(1),K(2) staged; QK(0) -> stA
  stageK(0, 0);
  stageV(0, 0);
  stageK(64, 1);
  stageK(128, 2);
  asm volatile("s_waitcnt vmcnt(12)" ::: "memory");  // K(0) landed
  __builtin_amdgcn_sched_barrier(0);
  __builtin_amdgcn_s_barrier();

  f32x16 stA0 = 0.0f, stA1 = 0.0f, stB0, stB1;
  {
    const bf16* krow0 = &sh[0] + (size_t)l31 * 128;
    const bf16* krow1 = krow0 + 32 * 128;
    __builtin_amdgcn_s_setprio(1);
#pragma unroll
    for (int ks = 0; ks < 8; ++ks) {
      int cb = ((ks * 32) ^ kxor) >> 1;
      bf16x8 kf0 = *(const bf16x8*)(krow0 + cb);
      bf16x8 kf1 = *(const bf16x8*)(krow1 + cb);
      stA0 = __builtin_amdgcn_mfma_f32_32x32x16_bf16(kf0, qf[ks], stA0, 0, 0, 0);
      stA1 = __builtin_amdgcn_mfma_f32_32x32x16_bf16(kf1, qf[ks], stA1, 0, 0, 0);
    }
    __builtin_amdgcn_s_setprio(0);
  }
  asm volatile("s_waitcnt vmcnt(4)" ::: "memory");  // V(0), K(1) landed; K(2) flies
  __builtin_amdgcn_sched_barrier(0);
  __builtin_amdgcn_s_barrier();

  int kb_st = 0;  // buffer for K(t+3) staged in body t: (t+3)%3 = t%3
  int kb_rd = 1;  // buffer of K(t+1) read in body t: (t+1)%3
  const int nt = qb / 64 + 2;
  int t = 0;
  for (; t + 1 < nt; t += 2) {
    FBODY(t, stA0, stA1, stB0, stB1);
    FBODY(t + 1, stB0, stB1, stA0, stA1);
  }
  if (t < nt) FBODY(t, stA0, stA1, stB0, stB1);

  // drain all flying stages before reusing LDS for the O transpose
  asm volatile("s_waitcnt vmcnt(0)" ::: "memory");
  __builtin_amdgcn_s_barrier();

  // epilogue: O^T -> LDS (swizzled) -> coalesced global
  float inv = 1.0f / l_run;
  bf16* ow = &sh[w * 4096];  // 32 rows x 128 cols per wave
#pragma unroll
  for (int n = 0; n < 4; ++n)
#pragma unroll
    for (int rq = 0; rq < 4; ++rq) {
      int dbase = 32 * n + 8 * rq + 4 * h;
      unsigned u0 = cvtpk(ot[n][4 * rq + 0] * inv, ot[n][4 * rq + 1] * inv);
      unsigned u1 = cvtpk(ot[n][4 * rq + 2] * inv, ot[n][4 * rq + 3] * inv);
      uint2 uu = make_uint2(u0, u1);
      *(uint2*)(ow + l31 * 128 + (dbase ^ ((l31 & 15) << 3))) = uu;
    }
  __syncthreads();
#pragma unroll
  for (int p = 0; p < 8; ++p) {
    int qr = p * 4 + (lane >> 4);
    int ce = ((((lane & 15) << 4) ^ ((qr & 15) << 4)) >> 1);
    bf16x8 vrow = *(const bf16x8*)(ow + qr * 128 + ce);
    *(bf16x8*)(O + (size_t)(b * S_LEN + qw0 + qr) * D_DIM + hh * HD + (lane & 15) * 8) = vrow;
  }
}

// ---------------- launch ----------------

extern "C" void kernel_launch(void* const* d_in, const int* in_sizes, int n_in,
                              void* d_out, int out_size, void* d_ws, size_t ws_size,
                              hipStream_t stream) {
  (void)in_sizes; (void)n_in; (void)out_size; (void)ws_size;
  const float* x  = (const float*)d_in[0];
  const float* wq = (const float*)d_in[1];
  const float* wk = (const float*)d_in[2];
  const float* wv = (const float*)d_in[3];
  const float* wo = (const float*)d_in[4];
  float* out = (float*)d_out;

  char* ws = (char*)d_ws;
  const size_t MB = 1u << 20;
  bf16* xb    = (bf16*)(ws + 0 * MB);    // 16MB; reused as O after attention
  bf16* Ob    = xb;
  bf16* wTall = (bf16*)(ws + 16 * MB);   // 24MB: wq^T | wk^T | wv^T rows
  bf16* wTo   = (bf16*)(ws + 40 * MB);   // 8MB
  bf16* QKV   = (bf16*)(ws + 48 * MB);   // 48MB: [4096][6144] (V slice unused)
  bf16* Vtb   = (bf16*)(ws + 96 * MB);   // 16MB
  float2* tab = (float2*)(ws + 112 * MB);

  rope_table_k<<<512, 256, 0, stream>>>(tab);
  convert_x_k<<<8192, 256, 0, stream>>>(x, xb);
  transpose_w_k<<<dim3(32, 32, 4), 256, 0, stream>>>(wq, wk, wv, wo, wTall, wTo);

  // fused QKV projection + RoPE + V-transpose
  gemm_qkv_k<<<dim3(QKV_STR / 128, NROW / 128), 256, 0, stream>>>(
      xb, wTall, QKV, Vtb, tab);

  flash_attn_k<<<dim3(S_LEN / 128, NB * NH), 256, 0, stream>>>(
      QKV, QKV + 2048, Vtb, Ob);

  gemm_bt_k<float><<<dim3(D_DIM / 128, NROW / 128), 256, 0, stream>>>(
      Ob, wTo, out, NROW, D_DIM, D_DIM);
}

// Round 13
// 284.525 us; speedup vs baseline: 1.0182x; 1.0182x over previous
//
#include <hip/hip_runtime.h>

#define S_LEN 2048
#define D_DIM 2048
#define NH 16
#define HD 128
#define NB 2
#define NROW (NB * S_LEN)  // 4096
#define QKV_STR 6144       // fused Q|K|V row stride (V slice unused/unwritten)

typedef unsigned short bf16;
typedef __attribute__((ext_vector_type(8))) short bf16x8;
typedef __attribute__((ext_vector_type(4))) float f32x4;
typedef __attribute__((ext_vector_type(16))) float f32x16;
typedef __attribute__((address_space(3))) unsigned int as3u;
typedef __attribute__((address_space(1))) unsigned int as1u;

__device__ __forceinline__ void gload16(const void* g, void* l) {
  __builtin_amdgcn_global_load_lds((const as1u*)g, (as3u*)l, 16, 0, 0);
}

__device__ __forceinline__ unsigned short f2bf(float f) {
  unsigned u = __builtin_bit_cast(unsigned, f);
  u += 0x7FFFu + ((u >> 16) & 1u);
  return (unsigned short)(u >> 16);
}
__device__ __forceinline__ float bf2f(unsigned short b) {
  return __builtin_bit_cast(float, (unsigned)b << 16);
}
__device__ __forceinline__ unsigned cvtpk(float lo, float hi) {
  unsigned r;
  asm("v_cvt_pk_bf16_f32 %0, %1, %2" : "=v"(r) : "v"(lo), "v"(hi));
  return r;
}
__device__ __forceinline__ float exp2a(float x) {  // 2^x
  float r;
  asm("v_exp_f32 %0, %1" : "=v"(r) : "v"(x));
  return r;
}

// ---------------- small prep kernels ----------------

__global__ void rope_table_k(float2* __restrict__ tab) {
  int i = blockIdx.x * 256 + threadIdx.x;  // S*64
  int s = i >> 6, d = i & 63;
  float invf = powf(10000.0f, -(float)d * (1.0f / 64.0f));
  float ang = (float)s * invf;
  tab[i] = make_float2(cosf(ang), sinf(ang));
}

__global__ void convert_x_k(const float* __restrict__ src, bf16* __restrict__ dst) {
  int i = (blockIdx.x * 256 + threadIdx.x) * 4;
  float4 v = *(const float4*)(src + i);
  ushort4 w;
  w.x = f2bf(v.x); w.y = f2bf(v.y); w.z = f2bf(v.z); w.w = f2bf(v.w);
  *(ushort4*)(dst + i) = w;
}

// all 4 weight transposes in one launch: z in {0:wq,1:wk,2:wv,3:wo}
__global__ void transpose_w_k(const float* __restrict__ w0, const float* __restrict__ w1,
                              const float* __restrict__ w2, const float* __restrict__ w3,
                              bf16* __restrict__ wTall, bf16* __restrict__ wTo) {
  __shared__ float t[64][65];
  int z = blockIdx.z;
  const float* W = (z == 0) ? w0 : (z == 1) ? w1 : (z == 2) ? w2 : w3;
  bf16* Wt = (z == 3) ? wTo : wTall + (size_t)z * 2048 * D_DIM;
  int c0 = blockIdx.x * 64, r0 = blockIdx.y * 64;
  int tx = threadIdx.x & 63, ty = threadIdx.x >> 6;
#pragma unroll
  for (int i = 0; i < 16; ++i)
    t[ty + i * 4][tx] = W[(size_t)(r0 + ty + i * 4) * D_DIM + c0 + tx];
  __syncthreads();
#pragma unroll
  for (int i = 0; i < 16; ++i)
    Wt[(size_t)(c0 + ty + i * 4) * D_DIM + r0 + tx] = f2bf(t[tx][ty + i * 4]);
}

// ---------------- 128x128 GEMM, BK=64 (m97 structure; WO projection) ---------

__device__ __forceinline__ void storec(bf16* p, float v) { *p = f2bf(v); }
__device__ __forceinline__ void storec(float* p, float v) { *p = v; }

template <typename OutT>
__global__ __launch_bounds__(256) void gemm_bt_k(
    const bf16* __restrict__ A, const bf16* __restrict__ Bt,
    OutT* __restrict__ C, int M, int N, int K) {
  __shared__ bf16 As[128 * 64];
  __shared__ bf16 Bs[128 * 64];
  const int tid = threadIdx.x;
  const int lane = tid & 63;
  const int wid = tid >> 6;
  const int bm = blockIdx.y * 128;
  const int bn = blockIdx.x * 128;
  const int wr = (wid >> 1) * 64;
  const int wc = (wid & 1) * 64;
  const int lr = lane & 15;
  const int kg = lane >> 4;

  f32x4 acc[4][4] = {};

  const int srow = lane >> 3;
  const int scol = ((lane & 7) ^ srow) * 8;
  const bf16* Ap = A + (size_t)(bm + wid * 32 + srow) * K + scol;
  const bf16* Bp = Bt + (size_t)(bn + wid * 32 + srow) * K + scol;
  bf16* Asd = &As[wid * 32 * 64];
  bf16* Bsd = &Bs[wid * 32 * 64];

  const int rx = (lr & 7) << 4;

  for (int k0 = 0; k0 < K; k0 += 64) {
    __syncthreads();
#pragma unroll
    for (int p = 0; p < 4; ++p) {
      gload16(Ap + (size_t)(p * 8) * K + k0, Asd + p * 8 * 64);
      gload16(Bp + (size_t)(p * 8) * K + k0, Bsd + p * 8 * 64);
    }
    __syncthreads();
    bf16x8 a[4][2], b[4][2];
#pragma unroll
    for (int m = 0; m < 4; ++m) {
      const char* rowp = (const char*)&As[(wr + m * 16 + lr) * 64];
#pragma unroll
      for (int kk = 0; kk < 2; ++kk)
        a[m][kk] = *(const bf16x8*)(rowp + ((kk * 64 + kg * 16) ^ rx));
    }
#pragma unroll
    for (int n = 0; n < 4; ++n) {
      const char* rowp = (const char*)&Bs[(wc + n * 16 + lr) * 64];
#pragma unroll
      for (int kk = 0; kk < 2; ++kk)
        b[n][kk] = *(const bf16x8*)(rowp + ((kk * 64 + kg * 16) ^ rx));
    }
#pragma unroll
    for (int kk = 0; kk < 2; ++kk)
#pragma unroll
      for (int m = 0; m < 4; ++m)
#pragma unroll
        for (int n = 0; n < 4; ++n)
          acc[m][n] = __builtin_amdgcn_mfma_f32_16x16x32_bf16(a[m][kk], b[n][kk], acc[m][n], 0, 0, 0);
  }

#pragma unroll
  for (int m = 0; m < 4; ++m) {
    int row0 = bm + wr + m * 16 + kg * 4;
#pragma unroll
    for (int n = 0; n < 4; ++n) {
      int col = bn + wc + n * 16 + lr;
#pragma unroll
      for (int r = 0; r < 4; ++r)
        storec(&C[(size_t)(row0 + r) * N + col], acc[m][n][r]);
    }
  }
}

// ---------------- QKV GEMM with fused RoPE + V-transpose epilogue ------------
// BK=64 main loop; wave column fragments remapped so each wave owns BOTH d and
// d+64 of a head: bcol(n) = wc2 + (n&1)*16 + (n>>1)*64. RoPE pair =
// (acc[m][n], acc[m][n+2]) in the SAME lane -> rope in f32 in-register.
// Direct scattered stores (R11-verified faster than LDS-bounce epilogue, R12).
__global__ __launch_bounds__(256) void gemm_qkv_k(
    const bf16* __restrict__ A, const bf16* __restrict__ Bt,
    bf16* __restrict__ QKV, bf16* __restrict__ Vt,
    const float2* __restrict__ tab) {
  const int K = 2048;
  __shared__ bf16 As[128 * 64];
  __shared__ bf16 Bs[128 * 64];
  const int tid = threadIdx.x;
  const int lane = tid & 63;
  const int wid = tid >> 6;
  const int bm = blockIdx.y * 128;
  const int bn = blockIdx.x * 128;
  const int wr = (wid >> 1) * 64;
  const int wc2 = (wid & 1) * 32;
  const int lr = lane & 15;
  const int kg = lane >> 4;

  f32x4 acc[4][4] = {};

  const int srow = lane >> 3;
  const int scol = ((lane & 7) ^ srow) * 8;
  const bf16* Ap = A + (size_t)(bm + wid * 32 + srow) * K + scol;
  const bf16* Bp = Bt + (size_t)(bn + wid * 32 + srow) * K + scol;
  bf16* Asd = &As[wid * 32 * 64];
  bf16* Bsd = &Bs[wid * 32 * 64];

  const int rx = (lr & 7) << 4;

  for (int k0 = 0; k0 < K; k0 += 64) {
    __syncthreads();
#pragma unroll
    for (int p = 0; p < 4; ++p) {
      gload16(Ap + (size_t)(p * 8) * K + k0, Asd + p * 8 * 64);
      gload16(Bp + (size_t)(p * 8) * K + k0, Bsd + p * 8 * 64);
    }
    __syncthreads();
    bf16x8 a[4][2], b[4][2];
#pragma unroll
    for (int m = 0; m < 4; ++m) {
      const char* rowp = (const char*)&As[(wr + m * 16 + lr) * 64];
#pragma unroll
      for (int kk = 0; kk < 2; ++kk)
        a[m][kk] = *(const bf16x8*)(rowp + ((kk * 64 + kg * 16) ^ rx));
    }
#pragma unroll
    for (int n = 0; n < 4; ++n) {
      int bcol = wc2 + (n & 1) * 16 + (n >> 1) * 64;  // remapped col fragment
      const char* rowp = (const char*)&Bs[(bcol + lr) * 64];
#pragma unroll
      for (int kk = 0; kk < 2; ++kk)
        b[n][kk] = *(const bf16x8*)(rowp + ((kk * 64 + kg * 16) ^ rx));
    }
#pragma unroll
    for (int kk = 0; kk < 2; ++kk)
#pragma unroll
      for (int m = 0; m < 4; ++m)
#pragma unroll
        for (int n = 0; n < 4; ++n)
          acc[m][n] = __builtin_amdgcn_mfma_f32_16x16x32_bf16(a[m][kk], b[n][kk], acc[m][n], 0, 0, 0);
  }

  if (bn < 4096) {
    // Q or K tile: fused RoPE. pair (d, d+64) = (acc[m][j], acc[m][j+2])
    const float sc = (bn < 2048) ? 0.12751743f : 1.0f;  // qscale = rsqrt(128)*log2e
#pragma unroll
    for (int m = 0; m < 4; ++m) {
      int row0 = bm + wr + m * 16 + kg * 4;
#pragma unroll
      for (int j = 0; j < 2; ++j) {
        int d = wc2 + j * 16 + lr;  // 0..63
#pragma unroll
        for (int r = 0; r < 4; ++r) {
          int s_pos = (row0 + r) & (S_LEN - 1);
          float2 cs = tab[s_pos * 64 + d];
          float x1 = acc[m][j][r], x2 = acc[m][j + 2][r];
          bf16* rowp = QKV + (size_t)(row0 + r) * QKV_STR + bn + d;
          rowp[0]  = f2bf((x1 * cs.x - x2 * cs.y) * sc);
          rowp[64] = f2bf((x2 * cs.x + x1 * cs.y) * sc);
        }
      }
    }
  } else {
    // V tile: write transposed Vt[bh][d][s], 4 consecutive s per 8B store
    int b = bm >> 11;
    int h = (bn - 4096) >> 7;
    bf16* vt = Vt + (size_t)(b * 16 + h) * HD * S_LEN;
#pragma unroll
    for (int m = 0; m < 4; ++m) {
      int s = (bm + wr + m * 16 + kg * 4) & (S_LEN - 1);
#pragma unroll
      for (int n = 0; n < 4; ++n) {
        int d = wc2 + (n & 1) * 16 + (n >> 1) * 64 + lr;
        ushort4 pk;
        pk.x = f2bf(acc[m][n][0]); pk.y = f2bf(acc[m][n][1]);
        pk.z = f2bf(acc[m][n][2]); pk.w = f2bf(acc[m][n][3]);
        *(ushort4*)(vt + (size_t)d * S_LEN + s) = pk;
      }
    }
  }
}

// ---------------- causal flash attention, 32x32 swapped, counted-vmcnt -------
// LDS 80KB: K triple-buffered, V double-buffered; 2 blocks/CU. Complementary
// strip lengths balance CU slot-pairs. T5 setprio around MFMA clusters (R12 win).
#define FBODY(T, CUR0, CUR1, NXT0, NXT1)                                         \
  {                                                                              \
    const int kv0_ = (T) * 64;                                                   \
    stageV(kv0_ + 64, ((T) + 1) & 1);                                            \
    stageK(kv0_ + 192, kb_st);                                                   \
    kb_st = (kb_st == 2) ? 0 : kb_st + 1;                                        \
    if (kv0_ + 64 <= qw0 + 31) {                                                 \
      NXT0 = 0.0f; NXT1 = 0.0f;                                                  \
      const bf16* krow0_ = &sh[kb_rd * 8192] + (size_t)l31 * 128;                \
      const bf16* krow1_ = krow0_ + 32 * 128;                                    \
      __builtin_amdgcn_s_setprio(1);                                             \
      _Pragma("unroll")                                                          \
      for (int ks = 0; ks < 8; ++ks) {                                           \
        int cb_ = ((ks * 32) ^ kxor) >> 1;                                       \
        bf16x8 kf0_ = *(const bf16x8*)(krow0_ + cb_);                            \
        bf16x8 kf1_ = *(const bf16x8*)(krow1_ + cb_);                            \
        NXT0 = __builtin_amdgcn_mfma_f32_32x32x16_bf16(kf0_, qf[ks], NXT0, 0, 0, 0); \
        NXT1 = __builtin_amdgcn_mfma_f32_32x32x16_bf16(kf1_, qf[ks], NXT1, 0, 0, 0); \
      }                                                                          \
      __builtin_amdgcn_s_setprio(0);                                             \
    }                                                                            \
    kb_rd = (kb_rd == 2) ? 0 : kb_rd + 1;                                        \
    if (kv0_ <= qw0 + 31) {                                                      \
      if (kv0_ + 63 > qw0) {                                                     \
        _Pragma("unroll")                                                        \
        for (int r = 0; r < 16; ++r) {                                           \
          int kvg_ = kv0_ + (r & 3) + 8 * (r >> 2) + 4 * h;                      \
          if (kvg_ > q) CUR0[r] = -3.0e38f;                                      \
          if (kvg_ + 32 > q) CUR1[r] = -3.0e38f;                                 \
        }                                                                        \
      }                                                                          \
      float tm_[8];                                                              \
      _Pragma("unroll")                                                          \
      for (int r = 0; r < 8; ++r)                                                \
        tm_[r] = fmaxf(fmaxf(CUR0[r], CUR0[r + 8]), fmaxf(CUR1[r], CUR1[r + 8])); \
      _Pragma("unroll")                                                          \
      for (int r = 0; r < 4; ++r) tm_[r] = fmaxf(tm_[r], tm_[r + 4]);            \
      float mt_ = fmaxf(fmaxf(tm_[0], tm_[1]), fmaxf(tm_[2], tm_[3]));           \
      mt_ = fmaxf(mt_, __shfl_xor(mt_, 32));                                     \
      if (__any(mt_ > m_run + 8.0f)) {                                           \
        float mnew_ = fmaxf(m_run, mt_);                                         \
        float alpha_ = exp2a(m_run - mnew_);                                     \
        l_run *= alpha_;                                                         \
        _Pragma("unroll")                                                        \
        for (int n = 0; n < 4; ++n)                                              \
          _Pragma("unroll")                                                      \
          for (int r = 0; r < 16; ++r) ot[n][r] *= alpha_;                       \
        m_run = mnew_;                                                           \
      }                                                                          \
      float rs_[16];                                                             \
      _Pragma("unroll")                                                          \
      for (int r = 0; r < 16; ++r) {                                             \
        CUR0[r] = exp2a(CUR0[r] - m_run);                                        \
        CUR1[r] = exp2a(CUR1[r] - m_run);                                        \
        rs_[r] = CUR0[r] + CUR1[r];                                              \
      }                                                                          \
      _Pragma("unroll")                                                          \
      for (int r = 0; r < 8; ++r) rs_[r] += rs_[r + 8];                          \
      _Pragma("unroll")                                                          \
      for (int r = 0; r < 4; ++r) rs_[r] += rs_[r + 4];                          \
      float rsum_ = (rs_[0] + rs_[1]) + (rs_[2] + rs_[3]);                       \
      rsum_ += __shfl_xor(rsum_, 32);                                            \
      l_run += rsum_;                                                            \
      unsigned wd0_[8], wd1_[8];                                                 \
      _Pragma("unroll")                                                          \
      for (int j = 0; j < 8; ++j) {                                              \
        wd0_[j] = cvtpk(CUR0[2 * j], CUR0[2 * j + 1]);                           \
        wd1_[j] = cvtpk(CUR1[2 * j], CUR1[2 * j + 1]);                           \
      }                                                                          \
      const bf16* Vbuf_ = &sh[24576 + ((T) & 1) * 8192];                         \
      __builtin_amdgcn_s_setprio(1);                                             \
      _Pragma("unroll")                                                          \
      for (int t4 = 0; t4 < 4; ++t4) {                                           \
        const unsigned* wdp_ = (t4 >> 1) ? wd1_ : wd0_;                          \
        int a0_ = 4 * (t4 & 1) + 2 * h;                                          \
        int sidx_ = 4 * (t4 & 1) + 2 * (1 - h);                                  \
        unsigned s0_ = (unsigned)__shfl_xor((int)wdp_[sidx_], 32);               \
        unsigned s1_ = (unsigned)__shfl_xor((int)wdp_[sidx_ + 1], 32);           \
        unsigned pb4_[4];                                                        \
        pb4_[0] = h ? s0_ : wdp_[a0_];                                           \
        pb4_[1] = h ? s1_ : wdp_[a0_ + 1];                                       \
        pb4_[2] = h ? wdp_[a0_] : s0_;                                           \
        pb4_[3] = h ? wdp_[a0_ + 1] : s1_;                                       \
        bf16x8 pb_ = __builtin_bit_cast(bf16x8, *(uint4*)pb4_);                  \
        int cb_ = ((t4 * 32) ^ vxor) >> 1;                                       \
        _Pragma("unroll")                                                        \
        for (int n = 0; n < 4; ++n) {                                            \
          bf16x8 va_ = *(const bf16x8*)(Vbuf_ + (size_t)(32 * n + l31) * 64 + cb_); \
          ot[n] = __builtin_amdgcn_mfma_f32_32x32x16_bf16(va_, pb_, ot[n], 0, 0, 0); \
        }                                                                        \
      }                                                                          \
      __builtin_amdgcn_s_setprio(0);                                             \
    }                                                                            \
    asm volatile("s_waitcnt vmcnt(4)" ::: "memory");                             \
    __builtin_amdgcn_sched_barrier(0);                                           \
    __builtin_amdgcn_s_barrier();                                                \
  }

__global__ __launch_bounds__(256, 2) void flash_attn_k(
    const bf16* __restrict__ Q, const bf16* __restrict__ Kb,
    const bf16* __restrict__ Vt, bf16* __restrict__ O) {
  __shared__ bf16 sh[40960];  // 80KB: K0/K1/K2 @0/8192/16384, V0/V1 @24576/32768
  const int tid = threadIdx.x;
  const int lane = tid & 63;
  const int w = tid >> 6;
  const int h = lane >> 5;
  const int l31 = lane & 31;
  const int bh = blockIdx.y;
  const int b = bh >> 4;
  const int hh = bh & 15;
  // complementary strip mapping: bh<16 long-first, bh>=16 short-first
  const int xr = (bh & 16) ? blockIdx.x : (gridDim.x - 1 - blockIdx.x);
  const int qb = xr * 128;
  const int qw0 = qb + 32 * w;
  const int q = qw0 + l31;

  const bf16* qp = Q + (size_t)(b * S_LEN + q) * QKV_STR + hh * HD + h * 8;
  bf16x8 qf[8];
#pragma unroll
  for (int ks = 0; ks < 8; ++ks) qf[ks] = *(const bf16x8*)(qp + ks * 16);

  f32x16 ot[4] = {};
  float m_run = -3.0e38f, l_run = 0.f;

  const bf16* Kg = Kb + (size_t)(b * S_LEN) * QKV_STR + hh * HD;
  const bf16* Vg = Vt + (size_t)bh * HD * S_LEN;

  const int kst_row = 16 * w + (lane >> 4);
  const int vst_row = 32 * w + (lane >> 3);
  const int vst_col = (((lane & 7) ^ (lane >> 3)) << 3);
  const int kxor = (16 * h) ^ ((l31 & 15) << 4);
  const int vxor = (16 * h) ^ ((l31 & 7) << 4);

  auto stageK = [&](int kv0, int buf) {
#pragma unroll
    for (int jj = 0; jj < 4; ++jj) {
      int kr = (kv0 + kst_row + jj * 4) & (S_LEN - 1);
      gload16(Kg + (size_t)kr * QKV_STR + (((lane & 15) ^ (jj * 4 + (lane >> 4))) << 3),
              &sh[buf * 8192 + (16 * w + jj * 4) * 128]);
    }
  };
  auto stageV = [&](int kv0, int buf) {
    int c = (kv0 & (S_LEN - 1)) + vst_col;
#pragma unroll
    for (int jj = 0; jj < 4; ++jj) {
      int vr = vst_row + jj * 8;
      gload16(Vg + (size_t)vr * S_LEN + c, &sh[24576 + buf * 8192 + (32 * w + jj * 8) * 64]);
    }
  };

  // prologue: K(0),V(0),K(1),K(2) staged; QK(0) -> stA
  stageK(0, 0);
  stageV(0, 0);
  stageK(64, 1);
  stageK(128, 2);
  asm volatile("s_waitcnt vmcnt(12)" ::: "memory");  // K(0) landed
  __builtin_amdgcn_sched_barrier(0);
  __builtin_amdgcn_s_barrier();

  f32x16 stA0 = 0.0f, stA1 = 0.0f, stB0, stB1;
  {
    const bf16* krow0 = &sh[0] + (size_t)l31 * 128;
    const bf16* krow1 = krow0 + 32 * 128;
    __builtin_amdgcn_s_setprio(1);
#pragma unroll
    for (int ks = 0; ks < 8; ++ks) {
      int cb = ((ks * 32) ^ kxor) >> 1;
      bf16x8 kf0 = *(const bf16x8*)(krow0 + cb);
      bf16x8 kf1 = *(const bf16x8*)(krow1 + cb);
      stA0 = __builtin_amdgcn_mfma_f32_32x32x16_bf16(kf0, qf[ks], stA0, 0, 0, 0);
      stA1 = __builtin_amdgcn_mfma_f32_32x32x16_bf16(kf1, qf[ks], stA1, 0, 0, 0);
    }
    __builtin_amdgcn_s_setprio(0);
  }
  asm volatile("s_waitcnt vmcnt(4)" ::: "memory");  // V(0), K(1) landed; K(2) flies
  __builtin_amdgcn_sched_barrier(0);
  __builtin_amdgcn_s_barrier();

  int kb_st = 0;  // buffer for K(t+3) staged in body t: (t+3)%3 = t%3
  int kb_rd = 1;  // buffer of K(t+1) read in body t: (t+1)%3
  const int nt = qb / 64 + 2;
  int t = 0;
  for (; t + 1 < nt; t += 2) {
    FBODY(t, stA0, stA1, stB0, stB1);
    FBODY(t + 1, stB0, stB1, stA0, stA1);
  }
  if (t < nt) FBODY(t, stA0, stA1, stB0, stB1);

  // drain all flying stages before reusing LDS for the O transpose
  asm volatile("s_waitcnt vmcnt(0)" ::: "memory");
  __builtin_amdgcn_s_barrier();

  // epilogue: O^T -> LDS (swizzled) -> coalesced global
  float inv = 1.0f / l_run;
  bf16* ow = &sh[w * 4096];  // 32 rows x 128 cols per wave
#pragma unroll
  for (int n = 0; n < 4; ++n)
#pragma unroll
    for (int rq = 0; rq < 4; ++rq) {
      int dbase = 32 * n + 8 * rq + 4 * h;
      unsigned u0 = cvtpk(ot[n][4 * rq + 0] * inv, ot[n][4 * rq + 1] * inv);
      unsigned u1 = cvtpk(ot[n][4 * rq + 2] * inv, ot[n][4 * rq + 3] * inv);
      uint2 uu = make_uint2(u0, u1);
      *(uint2*)(ow + l31 * 128 + (dbase ^ ((l31 & 15) << 3))) = uu;
    }
  __syncthreads();
#pragma unroll
  for (int p = 0; p < 8; ++p) {
    int qr = p * 4 + (lane >> 4);
    int ce = ((((lane & 15) << 4) ^ ((qr & 15) << 4)) >> 1);
    bf16x8 vrow = *(const bf16x8*)(ow + qr * 128 + ce);
    *(bf16x8*)(O + (size_t)(b * S_LEN + qw0 + qr) * D_DIM + hh * HD + (lane & 15) * 8) = vrow;
  }
}

// ---------------- launch ----------------

extern "C" void kernel_launch(void* const* d_in, const int* in_sizes, int n_in,
                              void* d_out, int out_size, void* d_ws, size_t ws_size,
                              hipStream_t stream) {
  (void)in_sizes; (void)n_in; (void)out_size; (void)ws_size;
  const float* x  = (const float*)d_in[0];
  const float* wq = (const float*)d_in[1];
  const float* wk = (const float*)d_in[2];
  const float* wv = (const float*)d_in[3];
  const float* wo = (const float*)d_in[4];
  float* out = (float*)d_out;

  char* ws = (char*)d_ws;
  const size_t MB = 1u << 20;
  bf16* xb    = (bf16*)(ws + 0 * MB);    // 16MB; reused as O after attention
  bf16* Ob    = xb;
  bf16* wTall = (bf16*)(ws + 16 * MB);   // 24MB: wq^T | wk^T | wv^T rows
  bf16* wTo   = (bf16*)(ws + 40 * MB);   // 8MB
  bf16* QKV   = (bf16*)(ws + 48 * MB);   // 48MB: [4096][6144] (V slice unused)
  bf16* Vtb   = (bf16*)(ws + 96 * MB);   // 16MB
  float2* tab = (float2*)(ws + 112 * MB);

  rope_table_k<<<512, 256, 0, stream>>>(tab);
  convert_x_k<<<8192, 256, 0, stream>>>(x, xb);
  transpose_w_k<<<dim3(32, 32, 4), 256, 0, stream>>>(wq, wk, wv, wo, wTall, wTo);

  // fused QKV projection + RoPE + V-transpose
  gemm_qkv_k<<<dim3(QKV_STR / 128, NROW / 128), 256, 0, stream>>>(
      xb, wTall, QKV, Vtb, tab);

  flash_attn_k<<<dim3(S_LEN / 128, NB * NH), 256, 0, stream>>>(
      QKV, QKV + 2048, Vtb, Ob);

  gemm_bt_k<float><<<dim3(D_DIM / 128, NROW / 128), 256, 0, stream>>>(
      Ob, wTo, out, NROW, D_DIM, D_DIM);
}